// Round 4
// baseline (410.926 us; speedup 1.0000x reference)
//
#include <hip/hip_runtime.h>
#include <math.h>

#define B_ 32
#define S_ 2048
#define H_ 1024
#define U_ 128

// workspace layout (float offsets)
#define OFF_V     0u          // 32*1024      = 32768
#define OFF_PM    32768u      // 1024
#define OFF_PL    33792u      // 1024
#define OFF_PCTX  34816u      // 1024*1024    = 1048576  (32 partials/batch)
#define OFF_VPART 1083392u    // 8*32*1024    = 262144
// total ~5.4 MB

typedef float vfloat4 __attribute__((ext_vector_type(4)));

static __device__ __forceinline__ float4 ntload4(const float* p) {
    vfloat4 v = __builtin_nontemporal_load((const vfloat4*)p);
    return make_float4(v.x, v.y, v.z, v.w);
}

// ---------------------------------------------------------------------------
// Kernel A: v_part[kc][b][h] = sum over k-chunk of W[h,k] * h_t[b,k]
__global__ __launch_bounds__(256) void k_vpart(const float* __restrict__ hid,
                                               const float* __restrict__ W,
                                               float* __restrict__ ws) {
    __shared__ float ht[32][128];   // 16 KB
    const int t  = threadIdx.x;
    const int h0 = blockIdx.x * 64;
    const int k0 = blockIdx.y * 128;
    #pragma unroll
    for (int i = 0; i < 4; ++i) {
        int f4 = i * 256 + t;
        int bl = f4 >> 5;
        int k4 = f4 & 31;
        float4 src = *(const float4*)(hid + ((size_t)bl * S_ + (S_ - 1)) * H_ + k0 + k4 * 4);
        *(float4*)&ht[bl][k4 * 4] = src;
    }
    __syncthreads();
    const int hl = t & 63;
    const int g  = t >> 6;
    const int h  = h0 + hl;
    float acc[8];
    #pragma unroll
    for (int i = 0; i < 8; ++i) acc[i] = 0.f;
    const float4* Wr = (const float4*)(W + (size_t)h * H_ + k0);
    for (int k4 = 0; k4 < 32; ++k4) {
        float4 w4 = Wr[k4];
        float wv[4] = {w4.x, w4.y, w4.z, w4.w};
        #pragma unroll
        for (int c = 0; c < 4; ++c) {
            float w = wv[c];
            int kk = k4 * 4 + c;
            #pragma unroll
            for (int bb = 0; bb < 8; ++bb)
                acc[bb] += w * ht[g * 8 + bb][kk];
        }
    }
    float* vpart = ws + OFF_VPART;
    const int kc = blockIdx.y;
    #pragma unroll
    for (int bb = 0; bb < 8; ++bb)
        vpart[((size_t)kc * 32 + (g * 8 + bb)) * H_ + h] = acc[bb];
}

// Kernel A2: v[b][h] = sum_kc v_part[kc][b][h]
__global__ __launch_bounds__(256) void k_vreduce(float* __restrict__ ws) {
    int e = blockIdx.x * 256 + threadIdx.x;   // < 32768
    const float* vp = ws + OFF_VPART;
    float s = 0.f;
    #pragma unroll
    for (int kc = 0; kc < 8; ++kc) s += vp[kc * 32768 + e];
    ws[OFF_V + e] = s;
}

// ---------------------------------------------------------------------------
// Kernel B: fused score + online softmax + context, flash-style.
// 1024 blocks (32/batch) x 256 thr; wave owns 16 rows, 4 rows/iter (16 float4
// in flight). Block-level merge in LDS -> ONE 4KB partial per block.
__global__ __launch_bounds__(256, 4) void k_flash(const float* __restrict__ hid,
                                                  float* __restrict__ ws) {
    const int t    = threadIdx.x;
    const int lane = t & 63;
    const int wave = t >> 6;
    const int b    = blockIdx.x >> 5;
    const int widx = blockIdx.x & 31;
    const int s0   = (widx * 4 + wave) * 16;

    const float* vrow = ws + OFF_V + (size_t)b * H_;
    float4 v4[4], c4[4];
    #pragma unroll
    for (int j = 0; j < 4; ++j) {
        v4[j] = *(const float4*)(vrow + j * 256 + lane * 4);
        c4[j] = make_float4(0.f, 0.f, 0.f, 0.f);
    }
    float m = -INFINITY, l = 0.f;
    const float* base = hid + ((size_t)b * S_ + s0) * H_ + lane * 4;

    for (int r = 0; r < 16; r += 4) {
        float4 rv[4][4];
        #pragma unroll
        for (int rr = 0; rr < 4; ++rr)
            #pragma unroll
            for (int j = 0; j < 4; ++j)
                rv[rr][j] = ntload4(base + (size_t)(r + rr) * H_ + j * 256);
        float p[4];
        #pragma unroll
        for (int rr = 0; rr < 4; ++rr) {
            float s = 0.f;
            #pragma unroll
            for (int j = 0; j < 4; ++j)
                s += rv[rr][j].x * v4[j].x + rv[rr][j].y * v4[j].y
                   + rv[rr][j].z * v4[j].z + rv[rr][j].w * v4[j].w;
            p[rr] = s;
        }
        #pragma unroll
        for (int off = 32; off > 0; off >>= 1) {
            #pragma unroll
            for (int rr = 0; rr < 4; ++rr) p[rr] += __shfl_xor(p[rr], off, 64);
        }
        float pmax = fmaxf(fmaxf(p[0], p[1]), fmaxf(p[2], p[3]));
        if (pmax > m) {                       // wave-uniform
            float alpha = __expf(m - pmax);   // first iter: exp(-inf)=0
            l *= alpha;
            #pragma unroll
            for (int j = 0; j < 4; ++j) {
                c4[j].x *= alpha; c4[j].y *= alpha; c4[j].z *= alpha; c4[j].w *= alpha;
            }
            m = pmax;
        }
        float e[4];
        #pragma unroll
        for (int rr = 0; rr < 4; ++rr) { e[rr] = __expf(p[rr] - m); l += e[rr]; }
        #pragma unroll
        for (int j = 0; j < 4; ++j) {
            #pragma unroll
            for (int rr = 0; rr < 4; ++rr) {
                c4[j].x += e[rr] * rv[rr][j].x;
                c4[j].y += e[rr] * rv[rr][j].y;
                c4[j].z += e[rr] * rv[rr][j].z;
                c4[j].w += e[rr] * rv[rr][j].w;
            }
        }
    }

    // block-level merge of the 4 waves' (m, l, c4)
    __shared__ float sml[8];
    __shared__ float sc[4][1024];   // 16 KB
    if (lane == 0) { sml[wave] = m; sml[4 + wave] = l; }
    __syncthreads();
    float M = fmaxf(fmaxf(sml[0], sml[1]), fmaxf(sml[2], sml[3]));
    float alpha = __expf(m - M);    // wave-uniform
    #pragma unroll
    for (int j = 0; j < 4; ++j) {
        float4 x = c4[j];
        x.x *= alpha; x.y *= alpha; x.z *= alpha; x.w *= alpha;
        *(float4*)&sc[wave][j * 256 + lane * 4] = x;
    }
    __syncthreads();
    float L = sml[4] * __expf(sml[0] - M) + sml[5] * __expf(sml[1] - M)
            + sml[6] * __expf(sml[2] - M) + sml[7] * __expf(sml[3] - M);
    const int pid = blockIdx.x;     // b*32 + widx
    float* pctx = ws + OFF_PCTX + (size_t)pid * H_;
    #pragma unroll
    for (int j = 0; j < 4; ++j) {
        int col = j * 256 + t;
        pctx[col] = sc[0][col] + sc[1][col] + sc[2][col] + sc[3][col];
    }
    if (t == 0) { ws[OFF_PM + pid] = M; ws[OFF_PL + pid] = L; }
}

// ---------------------------------------------------------------------------
// Kernel C: per-batch merge of 32 partials + output GEMM + tanh.
// grid 32 x 256. pre=[ctx, h_t] (2048) @ W2 (2048x128) -> tanh -> out.
__global__ __launch_bounds__(256) void k_mergeout(const float* __restrict__ hid,
                                                  const float* __restrict__ W2,
                                                  float* __restrict__ ws,
                                                  float* __restrict__ out) {
    const int b = blockIdx.x;
    const int t = threadIdx.x;
    __shared__ float pre[2048];     // 8 KB
    const float* pm = ws + OFF_PM + b * 32;
    const float* pl = ws + OFF_PL + b * 32;
    float M = -INFINITY;
    #pragma unroll
    for (int i = 0; i < 32; ++i) M = fmaxf(M, pm[i]);
    float L = 0.f;
    #pragma unroll
    for (int i = 0; i < 32; ++i) L += pl[i] * __expf(pm[i] - M);

    float acc[4] = {0.f, 0.f, 0.f, 0.f};
    const float* pctx = ws + OFF_PCTX + (size_t)b * 32 * H_;
    for (int i = 0; i < 32; ++i) {
        float w = __expf(pm[i] - M);
        #pragma unroll
        for (int j = 0; j < 4; ++j)
            acc[j] += w * pctx[(size_t)i * H_ + j * 256 + t];
    }
    float invL = 1.f / L;
    #pragma unroll
    for (int j = 0; j < 4; ++j) pre[j * 256 + t] = acc[j] * invL;
    float4 htv = *(const float4*)(hid + ((size_t)b * S_ + (S_ - 1)) * H_ + t * 4);
    *(float4*)&pre[1024 + t * 4] = htv;
    __syncthreads();

    const int u    = t & 127;
    const int half = t >> 7;        // wave-uniform (waves 0,1 -> 0; 2,3 -> 1)
    float s = 0.f;
    const float* p0 = pre + half * 1024;
    const float* w2 = W2 + (size_t)half * 1024 * U_ + u;
    #pragma unroll 8
    for (int j = 0; j < 1024; ++j) s += p0[j] * w2[(size_t)j * U_];
    __shared__ float red[256];
    red[t] = s;
    __syncthreads();
    if (t < 128) out[b * U_ + t] = tanhf(red[t] + red[t + 128]);
}

// ---------------------------------------------------------------------------
extern "C" void kernel_launch(void* const* d_in, const int* in_sizes, int n_in,
                              void* d_out, int out_size, void* d_ws, size_t ws_size,
                              hipStream_t stream) {
    const float* hid = (const float*)d_in[0];   // (32, 2048, 1024) fp32
    const float* W   = (const float*)d_in[1];   // (1024, 1024) fp32
    const float* W2  = (const float*)d_in[2];   // (2048, 128) fp32
    float* ws  = (float*)d_ws;
    float* out = (float*)d_out;                 // (32, 128) fp32

    hipLaunchKernelGGL(k_vpart,    dim3(16, 8), dim3(256), 0, stream, hid, W, ws);
    hipLaunchKernelGGL(k_vreduce,  dim3(128),   dim3(256), 0, stream, ws);
    hipLaunchKernelGGL(k_flash,    dim3(1024),  dim3(256), 0, stream, hid, ws);
    hipLaunchKernelGGL(k_mergeout, dim3(32),    dim3(256), 0, stream, hid, W2, ws, out);
}

// Round 5
// 392.774 us; speedup vs baseline: 1.0462x; 1.0462x over previous
//
#include <hip/hip_runtime.h>
#include <math.h>

#define B_ 32
#define S_ 2048
#define H_ 1024
#define U_ 128

// workspace layout (float offsets, all 16B-aligned)
#define OFF_VPART 0u          // 8*32*1024    = 262144
#define OFF_V     262144u     // 32*1024      = 32768
#define OFF_PM    294912u     // 32*128       = 4096
#define OFF_PL    299008u     // 32*128       = 4096
#define OFF_PCTX  303104u     // 32*128*1024  = 4194304
#define OFF_CTX   4497408u    // 32*1024      = 32768
#define OFF_DPART 4530176u    // 8*32*128     = 32768
// total ~18.3 MB

typedef float vfloat4 __attribute__((ext_vector_type(4)));

static __device__ __forceinline__ float4 ntload4(const float* p) {
    vfloat4 v = __builtin_nontemporal_load((const vfloat4*)p);
    return make_float4(v.x, v.y, v.z, v.w);
}

// ---------------------------------------------------------------------------
// Kernel A: v_part[kc][b][h] = sum over k-chunk of W[h,k] * h_t[b,k]
// grid (16, 8): h-chunks of 64, k-chunks of 128. 256 threads.
__global__ __launch_bounds__(256) void k_vpart(const float* __restrict__ hid,
                                               const float* __restrict__ W,
                                               float* __restrict__ ws) {
    __shared__ float ht[32][128];   // h_t slice for all 32 batches, 16 KB
    const int t  = threadIdx.x;
    const int h0 = blockIdx.x * 64;
    const int k0 = blockIdx.y * 128;
    #pragma unroll
    for (int i = 0; i < 4; ++i) {
        int f4 = i * 256 + t;            // 0..1023
        int bl = f4 >> 5;                // batch
        int k4 = f4 & 31;                // float4 within row
        float4 src = *(const float4*)(hid + ((size_t)bl * S_ + (S_ - 1)) * H_ + k0 + k4 * 4);
        *(float4*)&ht[bl][k4 * 4] = src;
    }
    __syncthreads();
    const int hl = t & 63;               // h within chunk
    const int g  = t >> 6;               // batch group (8 batches each)
    const int h  = h0 + hl;
    float acc[8];
    #pragma unroll
    for (int i = 0; i < 8; ++i) acc[i] = 0.f;
    const float4* Wr = (const float4*)(W + (size_t)h * H_ + k0);
    for (int k4 = 0; k4 < 32; ++k4) {
        float4 w4 = Wr[k4];
        float wv[4] = {w4.x, w4.y, w4.z, w4.w};
        #pragma unroll
        for (int c = 0; c < 4; ++c) {
            float w = wv[c];
            int kk = k4 * 4 + c;
            #pragma unroll
            for (int bb = 0; bb < 8; ++bb)
                acc[bb] += w * ht[g * 8 + bb][kk];
        }
    }
    float* vpart = ws + OFF_VPART;
    const int kc = blockIdx.y;
    #pragma unroll
    for (int bb = 0; bb < 8; ++bb)
        vpart[((size_t)kc * 32 + (g * 8 + bb)) * H_ + h] = acc[bb];
}

// Kernel A2: v[b][h] = sum_kc v_part[kc][b][h]
__global__ __launch_bounds__(256) void k_vreduce(float* __restrict__ ws) {
    int e = blockIdx.x * 256 + threadIdx.x;   // < 32768
    const float* vp = ws + OFF_VPART;
    float s = 0.f;
    #pragma unroll
    for (int kc = 0; kc < 8; ++kc) s += vp[kc * 32768 + e];
    ws[OFF_V + e] = s;
}

// ---------------------------------------------------------------------------
// Kernel B: fused score + online softmax + context partial, flash-style.
// One wave owns 16 consecutive s-rows, 4 rows/iter (16 float4 in flight).
// grid 1024 blocks x 256 threads = 4096 waves = 128 partials per batch.
// No launch-bound VGPR cap (R4's (256,4) likely spilled); no LDS merge.
__global__ __launch_bounds__(256) void k_flash(const float* __restrict__ hid,
                                               float* __restrict__ ws) {
    const int t    = threadIdx.x;
    const int lane = t & 63;
    const int wave = t >> 6;
    const int b    = blockIdx.x >> 5;
    const int wi   = (blockIdx.x & 31) * 4 + wave;   // 0..127 within batch
    const int s0   = wi * 16;

    const float* vrow = ws + OFF_V + (size_t)b * H_;
    float4 v4[4], c4[4];
    #pragma unroll
    for (int j = 0; j < 4; ++j) {
        v4[j] = *(const float4*)(vrow + j * 256 + lane * 4);
        c4[j] = make_float4(0.f, 0.f, 0.f, 0.f);
    }
    float m = -INFINITY, l = 0.f;
    const float* base = hid + ((size_t)b * S_ + s0) * H_ + lane * 4;

    for (int r = 0; r < 16; r += 4) {
        float4 rv[4][4];
        #pragma unroll
        for (int rr = 0; rr < 4; ++rr)
            #pragma unroll
            for (int j = 0; j < 4; ++j)
                rv[rr][j] = ntload4(base + (size_t)(r + rr) * H_ + j * 256);
        float p[4];
        #pragma unroll
        for (int rr = 0; rr < 4; ++rr) {
            float s = 0.f;
            #pragma unroll
            for (int j = 0; j < 4; ++j)
                s += rv[rr][j].x * v4[j].x + rv[rr][j].y * v4[j].y
                   + rv[rr][j].z * v4[j].z + rv[rr][j].w * v4[j].w;
            p[rr] = s;
        }
        #pragma unroll
        for (int off = 32; off > 0; off >>= 1) {
            #pragma unroll
            for (int rr = 0; rr < 4; ++rr) p[rr] += __shfl_xor(p[rr], off, 64);
        }
        float pmax = fmaxf(fmaxf(p[0], p[1]), fmaxf(p[2], p[3]));
        if (pmax > m) {                       // wave-uniform branch
            float alpha = __expf(m - pmax);   // first iter: exp(-inf)=0
            l *= alpha;
            #pragma unroll
            for (int j = 0; j < 4; ++j) {
                c4[j].x *= alpha; c4[j].y *= alpha; c4[j].z *= alpha; c4[j].w *= alpha;
            }
            m = pmax;
        }
        float e[4];
        #pragma unroll
        for (int rr = 0; rr < 4; ++rr) { e[rr] = __expf(p[rr] - m); l += e[rr]; }
        #pragma unroll
        for (int j = 0; j < 4; ++j) {
            #pragma unroll
            for (int rr = 0; rr < 4; ++rr) {
                c4[j].x += e[rr] * rv[rr][j].x;
                c4[j].y += e[rr] * rv[rr][j].y;
                c4[j].z += e[rr] * rv[rr][j].z;
                c4[j].w += e[rr] * rv[rr][j].w;
            }
        }
    }
    const int pid = b * 128 + wi;
    float* pctx = ws + OFF_PCTX + (size_t)pid * H_;
    #pragma unroll
    for (int j = 0; j < 4; ++j)
        *(float4*)(pctx + j * 256 + lane * 4) = c4[j];
    if (lane == 0) { ws[OFF_PM + pid] = m; ws[OFF_PL + pid] = l; }
}

// ---------------------------------------------------------------------------
// Kernel C: merge the 128 per-wave partials of each batch (exact softmax merge).
// grid (4 col-chunks, 32 batches) x 256; thread owns 1 context column.
__global__ __launch_bounds__(256) void k_merge(float* __restrict__ ws) {
    const int cc = blockIdx.x;
    const int b  = blockIdx.y;
    const int t  = threadIdx.x;
    const float* pm = ws + OFF_PM + b * 128;
    const float* pl = ws + OFF_PL + b * 128;
    float M = -INFINITY;
    #pragma unroll 8
    for (int i = 0; i < 128; ++i) M = fmaxf(M, pm[i]);
    float L = 0.f, c = 0.f;
    const float* pctx = ws + OFF_PCTX + (size_t)b * 128 * H_ + cc * 256 + t;
    #pragma unroll 4
    for (int i = 0; i < 128; ++i) {
        float w = __expf(pm[i] - M);
        L += pl[i] * w;
        c += w * pctx[(size_t)i * H_];
    }
    ws[OFF_CTX + (size_t)b * H_ + cc * 256 + t] = c / L;
}

// ---------------------------------------------------------------------------
// Kernel D1: partial output GEMM: pre=[ctx, h_t] (2048) @ W2 (2048x128), split J.
// grid (8 j-chunks, 32 batches) x 128 threads (one per unit).
__global__ __launch_bounds__(128) void k_out_part(const float* __restrict__ hid,
                                                  const float* __restrict__ W2,
                                                  float* __restrict__ ws) {
    __shared__ float pre[256];
    const int jc = blockIdx.x;
    const int b  = blockIdx.y;
    const int t  = threadIdx.x;
    #pragma unroll
    for (int i = 0; i < 2; ++i) {
        int idx = t * 2 + i;
        int j = jc * 256 + idx;
        float val = (j < 1024)
            ? ws[OFF_CTX + (size_t)b * H_ + j]
            : hid[((size_t)b * S_ + (S_ - 1)) * H_ + (j - 1024)];
        pre[idx] = val;
    }
    __syncthreads();
    float acc = 0.f;
    const float* w2 = W2 + (size_t)jc * 256 * U_ + t;
    #pragma unroll 8
    for (int jj = 0; jj < 256; ++jj)
        acc += pre[jj] * w2[(size_t)jj * U_];
    ws[OFF_DPART + ((size_t)jc * 32 + b) * U_ + t] = acc;
}

// Kernel D2: reduce J-chunks + tanh.
__global__ __launch_bounds__(256) void k_out_final(const float* __restrict__ ws,
                                                   float* __restrict__ out) {
    int idx = blockIdx.x * 256 + threadIdx.x;    // < 4096
    float s = 0.f;
    #pragma unroll
    for (int jc = 0; jc < 8; ++jc) s += ws[OFF_DPART + jc * 4096 + idx];
    out[idx] = tanhf(s);
}

// ---------------------------------------------------------------------------
extern "C" void kernel_launch(void* const* d_in, const int* in_sizes, int n_in,
                              void* d_out, int out_size, void* d_ws, size_t ws_size,
                              hipStream_t stream) {
    const float* hid = (const float*)d_in[0];   // (32, 2048, 1024) fp32
    const float* W   = (const float*)d_in[1];   // (1024, 1024) fp32
    const float* W2  = (const float*)d_in[2];   // (2048, 128) fp32
    float* ws  = (float*)d_ws;
    float* out = (float*)d_out;                 // (32, 128) fp32

    hipLaunchKernelGGL(k_vpart,     dim3(16, 8), dim3(256), 0, stream, hid, W, ws);
    hipLaunchKernelGGL(k_vreduce,   dim3(128),   dim3(256), 0, stream, ws);
    hipLaunchKernelGGL(k_flash,     dim3(1024),  dim3(256), 0, stream, hid, ws);
    hipLaunchKernelGGL(k_merge,     dim3(4, 32), dim3(256), 0, stream, ws);
    hipLaunchKernelGGL(k_out_part,  dim3(8, 32), dim3(128), 0, stream, hid, W2, ws);
    hipLaunchKernelGGL(k_out_final, dim3(16),    dim3(256), 0, stream, ws, out);
}